// Round 1
// baseline (69.852 us; speedup 1.0000x reference)
//
#include <hip/hip_runtime.h>
#include <math.h>

// Dendrite: B=8192, D=32, S=8, M=255.
// out[b,d] = lin_b + sum_{v=1..255} lin_w[v-1] * prod_{i: bit i of v set} s[b,d,7-i]
// where s[b,d,j] = sigmoid(k[d,j]*(w[d,j]*x[b,j] - q[d,j])).
// Subset products factor over nibbles: P(v) = Phi[v>>4] * Plo[v&15].

#define BLOCK 256

__global__ __launch_bounds__(BLOCK) void dendrite_kernel(
    const float* __restrict__ x,      // [B,1,S] flat, B*8
    const float* __restrict__ k,      // [D,S] flat, 256
    const float* __restrict__ w,      // [D,S]
    const float* __restrict__ q,      // [D,S]
    const float* __restrict__ lin_w,  // [1,M] flat, 255
    const float* __restrict__ lin_b,  // [1]
    float* __restrict__ out,          // [B,1,D] flat, B*32
    int total)                        // B*D
{
    // A[j][d] = k*w, Bc[j][d] = k*q, transposed so lane=d hits bank d.
    __shared__ float sA[8][32];
    __shared__ float sBc[8][32];
    __shared__ float s_lw[256];

    const int tid = threadIdx.x;
    {
        // one element per thread: flat t = d*8 + j
        const int d = tid >> 3, j = tid & 7;
        const float kk = k[tid];
        sA[j][d]  = kk * w[tid];
        sBc[j][d] = kk * q[tid];
        s_lw[tid] = (tid < 255) ? lin_w[tid] : 0.0f;
    }
    __syncthreads();

    const int gid = blockIdx.x * BLOCK + tid;
    if (gid >= total) return;
    const int b = gid >> 5;   // consecutive output addresses -> coalesced store
    const int d = gid & 31;

    // 32B of x per (b) row, broadcast across the 32 d-threads via L1.
    const float4* xv = (const float4*)(x + (size_t)b * 8);
    const float4 x0 = xv[0];
    const float4 x1 = xv[1];
    const float xx[8] = {x0.x, x0.y, x0.z, x0.w, x1.x, x1.y, x1.z, x1.w};

    float s[8];
#pragma unroll
    for (int j = 0; j < 8; ++j) {
        const float z = fmaf(sA[j][d], xx[j], -sBc[j][d]);
        s[j] = 1.0f / (1.0f + __expf(-z));   // sigmoid, in (0,1)
    }

    // Subset-product DP per nibble.
    // high nibble bit i' (i = i'+4 of v) -> s[7-i] = s[3-i']
    // low  nibble bit i                  -> s[7-i]
    float Phi[16], Plo[16];
    Phi[0] = 1.0f; Plo[0] = 1.0f;
#pragma unroll
    for (int v = 1; v < 16; ++v) {
        const int lb  = v & (-v);
        const int idx = (lb == 1) ? 0 : (lb == 2) ? 1 : (lb == 4) ? 2 : 3;
        Phi[v] = Phi[v ^ lb] * s[3 - idx];
        Plo[v] = Plo[v ^ lb] * s[7 - idx];
    }

    // acc = sum_h Phi[h] * sum_l lin_w[h*16+l-1] * Plo[l]
    float acc = 0.0f;
#pragma unroll
    for (int h = 0; h < 16; ++h) {
        float inner = 0.0f;
#pragma unroll
        for (int l = 0; l < 16; ++l) {
            const int v = (h << 4) | l;
            if (v == 0) continue;            // empty subset excluded (v starts at 1)
            inner = fmaf(s_lw[v - 1], Plo[l], inner);  // wave-uniform LDS broadcast
        }
        acc = fmaf(Phi[h], inner, acc);
    }
    out[gid] = acc + lin_b[0];
}

extern "C" void kernel_launch(void* const* d_in, const int* in_sizes, int n_in,
                              void* d_out, int out_size, void* d_ws, size_t ws_size,
                              hipStream_t stream) {
    // setup_inputs order: x, k, w, q, mask, lin_w, lin_b
    const float* x     = (const float*)d_in[0];
    const float* k     = (const float*)d_in[1];
    const float* w     = (const float*)d_in[2];
    const float* q     = (const float*)d_in[3];
    // d_in[4] = mask: structure is known (binary expansions 1..255), unused
    const float* lin_w = (const float*)d_in[5];
    const float* lin_b = (const float*)d_in[6];
    float* out = (float*)d_out;

    const int total = out_size;                 // B*D = 262144
    const int grid  = (total + BLOCK - 1) / BLOCK;
    dendrite_kernel<<<grid, BLOCK, 0, stream>>>(x, k, w, q, lin_w, lin_b, out, total);
}

// Round 2
// 69.091 us; speedup vs baseline: 1.0110x; 1.0110x over previous
//
#include <hip/hip_runtime.h>
#include <math.h>

// Dendrite: B=8192, D=32, S=8, M=255.
// out[b,d] = lin_b + sum_{v=1..255} lin_w[v-1] * prod_{i: bit i of v} s[b,d,7-i]
// s[b,d,j] = sigmoid(k[d,j]*(w[d,j]*x[b,j] - q[d,j]))
// Subset products factor over nibbles: P(v) = Phi[v>>4] * Plo[v&15].
// Weight table shifted by 1 (t[0]=0) so the v=0 "empty subset" term vanishes
// and all 16x16 rows are 64B-aligned for ds_read_b128.

#define BLOCK 256

__global__ __launch_bounds__(BLOCK) void dendrite_kernel(
    const float* __restrict__ x,      // [B,1,S]
    const float* __restrict__ k,      // [D,S]
    const float* __restrict__ w,      // [D,S]
    const float* __restrict__ q,      // [D,S]
    const float* __restrict__ lin_w,  // [1,M], M=255
    const float* __restrict__ lin_b,  // [1]
    float* __restrict__ out)          // [B,1,D]
{
    __shared__ float s_t[256];        // t[0]=0, t[v]=lin_w[v-1]

    const int tid = threadIdx.x;
    s_t[tid] = (tid == 0) ? 0.0f : lin_w[tid - 1];
    __syncthreads();

    const int gid = blockIdx.x * BLOCK + tid;   // grid exactly covers B*D
    const int b = gid >> 5;                     // coalesced store over d
    const int d = gid & 31;

    // x row: 32B, broadcast across the 32 d-lanes (L1).
    const float4* xv = (const float4*)(x + (size_t)b * 8);
    const float4 xa = xv[0], xb = xv[1];
    // k/w/q rows: lanes 0..31 cover 1KB contiguous -> coalesced; arrays are
    // 1KB each, L1-resident after first touch.
    const float4* kv = (const float4*)(k + d * 8);
    const float4 ka = kv[0], kb = kv[1];
    const float4* wv = (const float4*)(w + d * 8);
    const float4 wa = wv[0], wb = wv[1];
    const float4* qv = (const float4*)(q + d * 8);
    const float4 qa = qv[0], qb = qv[1];

    const float xx[8] = {xa.x, xa.y, xa.z, xa.w, xb.x, xb.y, xb.z, xb.w};
    const float kk[8] = {ka.x, ka.y, ka.z, ka.w, kb.x, kb.y, kb.z, kb.w};
    const float ww[8] = {wa.x, wa.y, wa.z, wa.w, wb.x, wb.y, wb.z, wb.w};
    const float qq[8] = {qa.x, qa.y, qa.z, qa.w, qb.x, qb.y, qb.z, qb.w};

    float s[8];
#pragma unroll
    for (int j = 0; j < 8; ++j) {
        const float z = kk[j] * fmaf(ww[j], xx[j], -qq[j]);
        const float e = __expf(-z);
        s[j] = __builtin_amdgcn_rcpf(1.0f + e);   // sigmoid; rcp approx ~1ulp
    }

    // Subset-product DP per nibble (fully unrolled, constant indices).
    // high-nibble bit i' (bit i'+4 of v) -> s[3-i']; low-nibble bit i -> s[7-i]
    float Phi[16], Plo[16];
    Phi[0] = 1.0f; Plo[0] = 1.0f;
#pragma unroll
    for (int v = 1; v < 16; ++v) {
        const int lb  = v & (-v);
        const int idx = (lb == 1) ? 0 : (lb == 2) ? 1 : (lb == 4) ? 2 : 3;
        Phi[v] = Phi[v ^ lb] * s[3 - idx];
        Plo[v] = Plo[v ^ lb] * s[7 - idx];
    }

    // acc = sum_h Phi[h] * (row_h . Plo), row_h = t[16h .. 16h+15]
    // Wave-uniform ds_read_b128 -> broadcast, 64 LDS ops total per thread.
    float acc = 0.0f;
#pragma unroll
    for (int h = 0; h < 16; ++h) {
        const float4* row = (const float4*)(s_t + (h << 4));
        const float4 r0 = row[0], r1 = row[1], r2 = row[2], r3 = row[3];
        float inner;
        inner = r0.x * Plo[0];
        inner = fmaf(r0.y, Plo[1],  inner);
        inner = fmaf(r0.z, Plo[2],  inner);
        inner = fmaf(r0.w, Plo[3],  inner);
        inner = fmaf(r1.x, Plo[4],  inner);
        inner = fmaf(r1.y, Plo[5],  inner);
        inner = fmaf(r1.z, Plo[6],  inner);
        inner = fmaf(r1.w, Plo[7],  inner);
        inner = fmaf(r2.x, Plo[8],  inner);
        inner = fmaf(r2.y, Plo[9],  inner);
        inner = fmaf(r2.z, Plo[10], inner);
        inner = fmaf(r2.w, Plo[11], inner);
        inner = fmaf(r3.x, Plo[12], inner);
        inner = fmaf(r3.y, Plo[13], inner);
        inner = fmaf(r3.z, Plo[14], inner);
        inner = fmaf(r3.w, Plo[15], inner);
        acc = fmaf(Phi[h], inner, acc);
    }
    out[gid] = acc + lin_b[0];
}

extern "C" void kernel_launch(void* const* d_in, const int* in_sizes, int n_in,
                              void* d_out, int out_size, void* d_ws, size_t ws_size,
                              hipStream_t stream) {
    // setup_inputs order: x, k, w, q, mask, lin_w, lin_b
    const float* x     = (const float*)d_in[0];
    const float* k     = (const float*)d_in[1];
    const float* w     = (const float*)d_in[2];
    const float* q     = (const float*)d_in[3];
    // d_in[4] = mask: binary expansions of 1..255, structure exploited, unused
    const float* lin_w = (const float*)d_in[5];
    const float* lin_b = (const float*)d_in[6];
    float* out = (float*)d_out;

    const int total = out_size;                 // B*D = 262144, multiple of 256
    const int grid  = total / BLOCK;
    dendrite_kernel<<<grid, BLOCK, 0, stream>>>(x, k, w, q, lin_w, lin_b, out);
}